// Round 6
// baseline (3362.816 us; speedup 1.0000x reference)
//
#include <hip/hip_runtime.h>

#define NCB 9
#define KCB 1024
#define CD 8
#define DD 64
#define TT 32768
#define BB 4

#define ZQ_SZ (BB*DD*TT)              // 8388608
#define CODES_OFF ZQ_SZ
#define CODES_SZ (BB*NCB*TT)          // 1179648
#define LAT_OFF (CODES_OFF + CODES_SZ)
#define LAT_SZ (BB*NCB*CD*TT)         // 9437184
#define LOSS_OFF (LAT_OFF + LAT_SZ)   // 19005440

// ---- d_ws byte layout ----
#define OFF_CBN32    0          // 73728 f32  = 294912
#define OFF_CBN64    294912     // 73728 f64  = 589824
#define OFF_SCBK64   884736     // 9216 f64   = 73728
#define OFF_WIN64    958464     // 4608 f64   = 36864
#define OFF_WOUT64   995328     // 4608 f64   = 36864
#define OFF_BIN64    1032192    // 72 f64     = 576
#define OFF_BOUT64   1032768    // 576 f64    = 4608
#define OFF_LOSSPART 1037376    // 1024 f64   = 8192

__global__ void prep_cb(const float* __restrict__ cb,
                        float* __restrict__ cbn32,
                        double* __restrict__ cbn64, double* __restrict__ scbk64) {
  int r = blockIdx.x * blockDim.x + threadIdx.x;
  if (r >= NCB * KCB) return;
  double v[CD], s = 0.0;
#pragma unroll
  for (int c = 0; c < CD; c++) { v[c] = (double)cb[r*CD + c]; s += v[c]*v[c]; }
  double den = fmax(sqrt(s), 1e-12);
  double s2 = 0.0;
#pragma unroll
  for (int c = 0; c < CD; c++) {
    double o = v[c] / den;
    cbn64[r*CD + c] = o;
    cbn32[r*CD + c] = (float)o;
    s2 += o*o;
  }
  scbk64[r] = s2;
}

__global__ void prep_w(const float* __restrict__ W_in, const float* __restrict__ b_in,
                       const float* __restrict__ W_out, const float* __restrict__ b_out,
                       double* __restrict__ Win64, double* __restrict__ bin64,
                       double* __restrict__ Wout64, double* __restrict__ bout64) {
  int i = blockIdx.x * blockDim.x + threadIdx.x;
  if (i < NCB*CD*DD) Win64[i]  = (double)W_in[i];
  if (i < NCB*CD*DD) Wout64[i] = (double)W_out[i];
  if (i < NCB*CD)    bin64[i]  = (double)b_in[i];
  if (i < NCB*DD)    bout64[i] = (double)b_out[i];
}

// Pair-split: lanes l and l+32 co-own position p. Each scans 512 codes and owns
// 32 D-channels; merges are one __shfl_xor(...,32) (f64 add -> bitwise exact).
// 128 positions/block -> grid 1024 -> 4 blocks/CU (LDS cap) = 4 waves/SIMD.
__global__ __launch_bounds__(256, 4) void rvq_kernel(
    const float* __restrict__ x,
    const float* __restrict__ cb,
    const double* __restrict__ Win64,
    const double* __restrict__ bin64,
    const double* __restrict__ Wout64,
    const double* __restrict__ bout64,
    const float* __restrict__ cbn32,
    const double* __restrict__ cbn64,
    const double* __restrict__ scbk64,
    float* __restrict__ out,
    double* __restrict__ loss_part) {
  __shared__ __align__(16) float cb_lds[KCB * CD];   // 32 KB
  __shared__ double wsum[4];

  const int lane = threadIdx.x & 63;
  const int wv   = threadIdx.x >> 6;
  const int h    = lane >> 5;                 // half: 0 or 1
  const int p    = blockIdx.x * 128 + wv * 32 + (lane & 31);
  const int b    = p >> 15;                   // TT = 2^15
  const int t    = p & (TT - 1);
  const int dbase = h * 32;

  // my 32 D-channels of the f64 residual chain
  double r[32];
#pragma unroll
  for (int d = 0; d < 32; d++) r[d] = (double)x[(b*DD + dbase + d)*TT + t];

  double lacc = 0.0;

#pragma unroll 1
  for (int i = 0; i < NCB; i++) {
    // ---- stage codebook i into LDS (row-major; scan reads are broadcast)
    __syncthreads();
    {
      const float4* __restrict__ src = (const float4*)(cbn32 + i*KCB*CD);
      float4* __restrict__ dst = (float4*)cb_lds;
#pragma unroll
      for (int c0 = 0; c0 < 8; c0++)
        dst[c0*256 + threadIdx.x] = src[c0*256 + threadIdx.x];
    }
    __syncthreads();

    // ---- in_proj (f64): partial over my 32 d's, one xor-32 merge
    double ze[CD];
    {
      const double* __restrict__ W = Win64 + i*CD*DD + dbase;
#pragma unroll
      for (int c = 0; c < CD; c++) {
        double acc = 0.0;
#pragma unroll
        for (int d = 0; d < 32; d++)
          acc = fma(W[c*DD + d], r[d], acc);
        ze[c] = acc;
      }
#pragma unroll
      for (int c = 0; c < CD; c++) {
        ze[c] += __shfl_xor(ze[c], 32, 64);   // bitwise identical on both lanes
        ze[c] += bin64[i*CD + c];
      }
    }

    // ---- normalize: one f64 division, f32 enc for the scan
    double s0 = 0.0;
#pragma unroll
    for (int c = 0; c < CD; c++) s0 = fma(ze[c], ze[c], s0);
    double inv = 1.0 / fmax(sqrt(s0), 1e-12);
    float encf[CD];
#pragma unroll
    for (int c = 0; c < CD; c++) encf[c] = (float)(ze[c] * inv);

    // ---- f32 max-dot scan of my 512 rows (top-2 via med3/max)
    const float* __restrict__ lbase = cb_lds + h * (512 * CD);
    float best = -3.402823466e38f, best2 = -3.402823466e38f;
    int bidx = 0;
#pragma unroll 8
    for (int kk = 0; kk < 512; kk++) {
      float4 r0 = *(const float4*)(lbase + kk*CD);
      float4 r1 = *(const float4*)(lbase + kk*CD + 4);
      float dot = encf[0] * r0.x;
      dot = fmaf(encf[1], r0.y, dot);
      dot = fmaf(encf[2], r0.z, dot);
      dot = fmaf(encf[3], r0.w, dot);
      dot = fmaf(encf[4], r1.x, dot);
      dot = fmaf(encf[5], r1.y, dot);
      dot = fmaf(encf[6], r1.z, dot);
      dot = fmaf(encf[7], r1.w, dot);
      float ob = best;
      best2 = __builtin_amdgcn_fmed3f(ob, best2, dot);
      best  = fmaxf(ob, dot);
      bidx  = (dot > ob) ? (h*512 + kk) : bidx;   // strict > => first index on ties
    }

    // ---- merge top-2 + argmax across the pair (xor 32)
    {
      float obest  = __shfl_xor(best, 32, 64);
      float obest2 = __shfl_xor(best2, 32, 64);
      int   okidx  = __shfl_xor(bidx, 32, 64);
      best2 = fmaxf(fminf(best, obest), fmaxf(best2, obest2));
      bool take = (obest > best) || (obest == best && okidx < bidx);
      best = fmaxf(best, obest);
      bidx = take ? okidx : bidx;
    }

    // ---- near-tie: authoritative f64 rescan (pair-uniform trigger, rare)
    if (best - best2 < 1.2e-5f) {
      const double* __restrict__ cb64 = cbn64 + (i*KCB + h*512)*CD;
      const double* __restrict__ s64  = scbk64 + i*KCB + h*512;
      double enc64[CD], s_enc = 0.0;
#pragma unroll
      for (int c = 0; c < CD; c++) {
        enc64[c] = ze[c] * inv;
        s_enc = fma(enc64[c], enc64[c], s_enc);
      }
      double bd = 1e300;
      int bk = 0x3fffffff;
#pragma unroll 2
      for (int kk = 0; kk < 512; kk++) {
        double dot = 0.0;
#pragma unroll
        for (int c = 0; c < CD; c++)
          dot = fma(enc64[c], cb64[kk*CD + c], dot);
        double dist = fma(-2.0, dot, s_enc) + s64[kk];
        if (dist < bd) { bd = dist; bk = h*512 + kk; }   // first index on ties
      }
      {
        double od = __shfl_xor(bd, 32, 64);
        int    ok = __shfl_xor(bk, 32, 64);
        bool take = (od < bd) || (od == bd && ok < bk);
        bd = take ? od : bd;
        bk = take ? ok : bk;
      }
      bidx = bk;
    }

    // ---- gather raw codebook row (pair-uniform address)
    const float4* __restrict__ qrow = (const float4*)(cb + (i*KCB + bidx)*CD);
    float4 q0 = qrow[0], q1 = qrow[1];
    double zq[CD] = {(double)q0.x, (double)q0.y, (double)q0.z, (double)q0.w,
                     (double)q1.x, (double)q1.y, (double)q1.z, (double)q1.w};

    // ---- loss once per position (h==0 half only)
    if (h == 0) {
#pragma unroll
      for (int c = 0; c < CD; c++) {
        double dlt = ze[c] - zq[c];
        lacc = fma(dlt, dlt, lacc);
      }
    }

    // ---- out_proj (f64) on my 32 d's + residual update
    {
      const double* __restrict__ Wo = Wout64 + (i*DD + dbase)*CD;
#pragma unroll
      for (int d = 0; d < 32; d++) {
        double acc = bout64[i*DD + dbase + d];
#pragma unroll
        for (int c = 0; c < CD; c++)
          acc = fma(Wo[d*CD + c], zq[c], acc);
        r[d] -= acc;
      }
    }

    // ---- codes (h==0) + latents (each half writes 4 channels)
    if (h == 0) out[CODES_OFF + (b*NCB + i)*TT + t] = (float)bidx;
#pragma unroll
    for (int cc = 0; cc < 4; cc++)
      out[LAT_OFF + (b*NCB*CD + i*CD + 4*h + cc)*TT + t] = (float)ze[4*h + cc];
  }

  // ---- z_q = x - residual_final (my 32 d's)
#pragma unroll
  for (int d = 0; d < 32; d++)
    out[(b*DD + dbase + d)*TT + t] =
        (float)((double)x[(b*DD + dbase + d)*TT + t] - r[d]);

  // ---- deterministic loss reduction (h==1 lanes hold 0)
#pragma unroll
  for (int off = 32; off > 0; off >>= 1)
    lacc += __shfl_down(lacc, off, 64);
  if ((threadIdx.x & 63) == 0) wsum[wv] = lacc;
  __syncthreads();
  if (threadIdx.x == 0)
    loss_part[blockIdx.x] = wsum[0] + wsum[1] + wsum[2] + wsum[3];
}

__global__ void loss_final(const double* __restrict__ loss_part,
                           float* __restrict__ out) {
  __shared__ double sh[256];
  double s = 0.0;
#pragma unroll
  for (int i = 0; i < 4; i++) s += loss_part[threadIdx.x + i*256];
  sh[threadIdx.x] = s;
  __syncthreads();
  for (int off = 128; off > 0; off >>= 1) {
    if (threadIdx.x < off) sh[threadIdx.x] += sh[threadIdx.x + off];
    __syncthreads();
  }
  if (threadIdx.x == 0) {
    double v = sh[0] / ((double)NCB * (double)BB * (double)CD * (double)TT);
    out[LOSS_OFF]     = (float)v;   // commit
    out[LOSS_OFF + 1] = (float)v;   // cb_loss (equal in forward value)
  }
}

extern "C" void kernel_launch(void* const* d_in, const int* in_sizes, int n_in,
                              void* d_out, int out_size, void* d_ws, size_t ws_size,
                              hipStream_t stream) {
  const float* x     = (const float*)d_in[0];
  const float* W_in  = (const float*)d_in[1];
  const float* b_in  = (const float*)d_in[2];
  const float* cb    = (const float*)d_in[3];
  const float* W_out = (const float*)d_in[4];
  const float* b_out = (const float*)d_in[5];
  float* out = (float*)d_out;

  char* ws = (char*)d_ws;
  float*  cbn32  = (float*)(ws + OFF_CBN32);
  double* cbn64  = (double*)(ws + OFF_CBN64);
  double* scbk64 = (double*)(ws + OFF_SCBK64);
  double* Win64  = (double*)(ws + OFF_WIN64);
  double* Wout64 = (double*)(ws + OFF_WOUT64);
  double* bin64  = (double*)(ws + OFF_BIN64);
  double* bout64 = (double*)(ws + OFF_BOUT64);
  double* loss_part = (double*)(ws + OFF_LOSSPART);

  prep_cb<<<(NCB*KCB + 255)/256, 256, 0, stream>>>(cb, cbn32, cbn64, scbk64);
  prep_w<<<(NCB*CD*DD + 255)/256, 256, 0, stream>>>(W_in, b_in, W_out, b_out,
                                                    Win64, bin64, Wout64, bout64);
  rvq_kernel<<<1024, 256, 0, stream>>>(x, cb, Win64, bin64, Wout64, bout64,
                                       cbn32, cbn64, scbk64, out, loss_part);
  loss_final<<<1, 256, 0, stream>>>(loss_part, out);
}

// Round 7
// 3358.381 us; speedup vs baseline: 1.0013x; 1.0013x over previous
//
#include <hip/hip_runtime.h>

#define NCB 9
#define KCB 1024
#define CD 8
#define DD 64
#define TT 32768
#define BB 4

#define ZQ_SZ (BB*DD*TT)              // 8388608
#define CODES_OFF ZQ_SZ
#define CODES_SZ (BB*NCB*TT)          // 1179648
#define LAT_OFF (CODES_OFF + CODES_SZ)
#define LAT_SZ (BB*NCB*CD*TT)         // 9437184
#define LOSS_OFF (LAT_OFF + LAT_SZ)   // 19005440

// ---- d_ws byte layout ----
#define OFF_CBN32    0          // 73728 f32  = 294912
#define OFF_CBN64    294912     // 73728 f64  = 589824
#define OFF_SCBK64   884736     // 9216 f64   = 73728
#define OFF_WIN64    958464     // 4608 f64   = 36864
#define OFF_WOUT64   995328     // 4608 f64   = 36864
#define OFF_BIN64    1032192    // 72 f64     = 576
#define OFF_BOUT64   1032768    // 576 f64    = 4608
#define OFF_LOSSPART 1037376    // 1024 f64   = 8192

__global__ void prep_cb(const float* __restrict__ cb,
                        float* __restrict__ cbn32,
                        double* __restrict__ cbn64, double* __restrict__ scbk64) {
  int r = blockIdx.x * blockDim.x + threadIdx.x;
  if (r >= NCB * KCB) return;
  double v[CD], s = 0.0;
#pragma unroll
  for (int c = 0; c < CD; c++) { v[c] = (double)cb[r*CD + c]; s += v[c]*v[c]; }
  double den = fmax(sqrt(s), 1e-12);
  double s2 = 0.0;
#pragma unroll
  for (int c = 0; c < CD; c++) {
    double o = v[c] / den;
    cbn64[r*CD + c] = o;
    cbn32[r*CD + c] = (float)o;
    s2 += o*o;
  }
  scbk64[r] = s2;
}

__global__ void prep_w(const float* __restrict__ W_in, const float* __restrict__ b_in,
                       const float* __restrict__ W_out, const float* __restrict__ b_out,
                       double* __restrict__ Win64, double* __restrict__ bin64,
                       double* __restrict__ Wout64, double* __restrict__ bout64) {
  int i = blockIdx.x * blockDim.x + threadIdx.x;
  if (i < NCB*CD*DD) Win64[i]  = (double)W_in[i];
  if (i < NCB*CD*DD) Wout64[i] = (double)W_out[i];
  if (i < NCB*CD)    bin64[i]  = (double)b_in[i];
  if (i < NCB*DD)    bout64[i] = (double)b_out[i];
}

// Pair-split: lanes l and l+32 co-own position p. Each scans 512 codes and owns
// 32 D-channels; merges are one __shfl_xor(...,32) (f64 add -> bitwise exact).
// waves_per_eu(4,4): clamp occupancy so the allocator gets the full 128-VGPR
// budget — launch_bounds(256,4) alone let the compiler chase 8 waves/EU and
// spill the f64 chain to scratch (R4/R6: VGPR=64, 8.5 GB scratch traffic).
__global__ __launch_bounds__(256)
__attribute__((amdgpu_waves_per_eu(4, 4)))
void rvq_kernel(
    const float* __restrict__ x,
    const float* __restrict__ cb,
    const double* __restrict__ Win64,
    const double* __restrict__ bin64,
    const double* __restrict__ Wout64,
    const double* __restrict__ bout64,
    const float* __restrict__ cbn32,
    const double* __restrict__ cbn64,
    const double* __restrict__ scbk64,
    float* __restrict__ out,
    double* __restrict__ loss_part) {
  __shared__ __align__(16) float cb_lds[KCB * CD];   // 32 KB
  __shared__ double wsum[4];

  const int lane = threadIdx.x & 63;
  const int wv   = threadIdx.x >> 6;
  const int h    = lane >> 5;                 // half: 0 or 1
  const int p    = blockIdx.x * 128 + wv * 32 + (lane & 31);
  const int b    = p >> 15;                   // TT = 2^15
  const int t    = p & (TT - 1);
  const int dbase = h * 32;

  // my 32 D-channels of the f64 residual chain
  double r[32];
#pragma unroll
  for (int d = 0; d < 32; d++) r[d] = (double)x[(b*DD + dbase + d)*TT + t];

  double lacc = 0.0;

#pragma unroll 1
  for (int i = 0; i < NCB; i++) {
    // ---- stage codebook i into LDS (row-major; scan reads are broadcast)
    __syncthreads();
    {
      const float4* __restrict__ src = (const float4*)(cbn32 + i*KCB*CD);
      float4* __restrict__ dst = (float4*)cb_lds;
#pragma unroll
      for (int c0 = 0; c0 < 8; c0++)
        dst[c0*256 + threadIdx.x] = src[c0*256 + threadIdx.x];
    }
    __syncthreads();

    // ---- in_proj (f64): partial over my 32 d's, one xor-32 merge
    double ze[CD];
    {
      const double* __restrict__ W = Win64 + i*CD*DD + dbase;
#pragma unroll
      for (int c = 0; c < CD; c++) {
        double acc = 0.0;
#pragma unroll
        for (int d = 0; d < 32; d++)
          acc = fma(W[c*DD + d], r[d], acc);
        ze[c] = acc;
      }
#pragma unroll
      for (int c = 0; c < CD; c++) {
        ze[c] += __shfl_xor(ze[c], 32, 64);   // bitwise identical on both lanes
        ze[c] += bin64[i*CD + c];
      }
    }

    // ---- normalize: one f64 division, f32 enc for the scan
    double s0 = 0.0;
#pragma unroll
    for (int c = 0; c < CD; c++) s0 = fma(ze[c], ze[c], s0);
    double inv = 1.0 / fmax(sqrt(s0), 1e-12);
    float encf[CD];
#pragma unroll
    for (int c = 0; c < CD; c++) encf[c] = (float)(ze[c] * inv);

    // ---- f32 max-dot scan of my 512 rows (top-2 via med3/max)
    const float* __restrict__ lbase = cb_lds + h * (512 * CD);
    float best = -3.402823466e38f, best2 = -3.402823466e38f;
    int bidx = 0;
#pragma unroll 8
    for (int kk = 0; kk < 512; kk++) {
      float4 r0 = *(const float4*)(lbase + kk*CD);
      float4 r1 = *(const float4*)(lbase + kk*CD + 4);
      float dot = encf[0] * r0.x;
      dot = fmaf(encf[1], r0.y, dot);
      dot = fmaf(encf[2], r0.z, dot);
      dot = fmaf(encf[3], r0.w, dot);
      dot = fmaf(encf[4], r1.x, dot);
      dot = fmaf(encf[5], r1.y, dot);
      dot = fmaf(encf[6], r1.z, dot);
      dot = fmaf(encf[7], r1.w, dot);
      float ob = best;
      best2 = __builtin_amdgcn_fmed3f(ob, best2, dot);
      best  = fmaxf(ob, dot);
      bidx  = (dot > ob) ? (h*512 + kk) : bidx;   // strict > => first index on ties
    }

    // ---- merge top-2 + argmax across the pair (xor 32)
    {
      float obest  = __shfl_xor(best, 32, 64);
      float obest2 = __shfl_xor(best2, 32, 64);
      int   okidx  = __shfl_xor(bidx, 32, 64);
      best2 = fmaxf(fminf(best, obest), fmaxf(best2, obest2));
      bool take = (obest > best) || (obest == best && okidx < bidx);
      best = fmaxf(best, obest);
      bidx = take ? okidx : bidx;
    }

    // ---- near-tie: authoritative f64 rescan (pair-uniform trigger, rare)
    if (best - best2 < 1.2e-5f) {
      const double* __restrict__ cb64 = cbn64 + (i*KCB + h*512)*CD;
      const double* __restrict__ s64  = scbk64 + i*KCB + h*512;
      double enc64[CD], s_enc = 0.0;
#pragma unroll
      for (int c = 0; c < CD; c++) {
        enc64[c] = ze[c] * inv;
        s_enc = fma(enc64[c], enc64[c], s_enc);
      }
      double bd = 1e300;
      int bk = 0x3fffffff;
#pragma unroll 2
      for (int kk = 0; kk < 512; kk++) {
        double dot = 0.0;
#pragma unroll
        for (int c = 0; c < CD; c++)
          dot = fma(enc64[c], cb64[kk*CD + c], dot);
        double dist = fma(-2.0, dot, s_enc) + s64[kk];
        if (dist < bd) { bd = dist; bk = h*512 + kk; }   // first index on ties
      }
      {
        double od = __shfl_xor(bd, 32, 64);
        int    ok = __shfl_xor(bk, 32, 64);
        bool take = (od < bd) || (od == bd && ok < bk);
        bd = take ? od : bd;
        bk = take ? ok : bk;
      }
      bidx = bk;
    }

    // ---- gather raw codebook row (pair-uniform address)
    const float4* __restrict__ qrow = (const float4*)(cb + (i*KCB + bidx)*CD);
    float4 q0 = qrow[0], q1 = qrow[1];
    double zq[CD] = {(double)q0.x, (double)q0.y, (double)q0.z, (double)q0.w,
                     (double)q1.x, (double)q1.y, (double)q1.z, (double)q1.w};

    // ---- loss once per position (h==0 half only)
    if (h == 0) {
#pragma unroll
      for (int c = 0; c < CD; c++) {
        double dlt = ze[c] - zq[c];
        lacc = fma(dlt, dlt, lacc);
      }
    }

    // ---- out_proj (f64) on my 32 d's + residual update
    {
      const double* __restrict__ Wo = Wout64 + (i*DD + dbase)*CD;
#pragma unroll
      for (int d = 0; d < 32; d++) {
        double acc = bout64[i*DD + dbase + d];
#pragma unroll
        for (int c = 0; c < CD; c++)
          acc = fma(Wo[d*CD + c], zq[c], acc);
        r[d] -= acc;
      }
    }

    // ---- codes (h==0) + latents (each half writes 4 channels)
    if (h == 0) out[CODES_OFF + (b*NCB + i)*TT + t] = (float)bidx;
#pragma unroll
    for (int cc = 0; cc < 4; cc++)
      out[LAT_OFF + (b*NCB*CD + i*CD + 4*h + cc)*TT + t] = (float)ze[4*h + cc];
  }

  // ---- z_q = x - residual_final (my 32 d's)
#pragma unroll
  for (int d = 0; d < 32; d++)
    out[(b*DD + dbase + d)*TT + t] =
        (float)((double)x[(b*DD + dbase + d)*TT + t] - r[d]);

  // ---- deterministic loss reduction (h==1 lanes hold 0)
#pragma unroll
  for (int off = 32; off > 0; off >>= 1)
    lacc += __shfl_down(lacc, off, 64);
  if ((threadIdx.x & 63) == 0) wsum[wv] = lacc;
  __syncthreads();
  if (threadIdx.x == 0)
    loss_part[blockIdx.x] = wsum[0] + wsum[1] + wsum[2] + wsum[3];
}

__global__ void loss_final(const double* __restrict__ loss_part,
                           float* __restrict__ out) {
  __shared__ double sh[256];
  double s = 0.0;
#pragma unroll
  for (int i = 0; i < 4; i++) s += loss_part[threadIdx.x + i*256];
  sh[threadIdx.x] = s;
  __syncthreads();
  for (int off = 128; off > 0; off >>= 1) {
    if (threadIdx.x < off) sh[threadIdx.x] += sh[threadIdx.x + off];
    __syncthreads();
  }
  if (threadIdx.x == 0) {
    double v = sh[0] / ((double)NCB * (double)BB * (double)CD * (double)TT);
    out[LOSS_OFF]     = (float)v;   // commit
    out[LOSS_OFF + 1] = (float)v;   // cb_loss (equal in forward value)
  }
}

extern "C" void kernel_launch(void* const* d_in, const int* in_sizes, int n_in,
                              void* d_out, int out_size, void* d_ws, size_t ws_size,
                              hipStream_t stream) {
  const float* x     = (const float*)d_in[0];
  const float* W_in  = (const float*)d_in[1];
  const float* b_in  = (const float*)d_in[2];
  const float* cb    = (const float*)d_in[3];
  const float* W_out = (const float*)d_in[4];
  const float* b_out = (const float*)d_in[5];
  float* out = (float*)d_out;

  char* ws = (char*)d_ws;
  float*  cbn32  = (float*)(ws + OFF_CBN32);
  double* cbn64  = (double*)(ws + OFF_CBN64);
  double* scbk64 = (double*)(ws + OFF_SCBK64);
  double* Win64  = (double*)(ws + OFF_WIN64);
  double* Wout64 = (double*)(ws + OFF_WOUT64);
  double* bin64  = (double*)(ws + OFF_BIN64);
  double* bout64 = (double*)(ws + OFF_BOUT64);
  double* loss_part = (double*)(ws + OFF_LOSSPART);

  prep_cb<<<(NCB*KCB + 255)/256, 256, 0, stream>>>(cb, cbn32, cbn64, scbk64);
  prep_w<<<(NCB*CD*DD + 255)/256, 256, 0, stream>>>(W_in, b_in, W_out, b_out,
                                                    Win64, bin64, Wout64, bout64);
  rvq_kernel<<<1024, 256, 0, stream>>>(x, cb, Win64, bin64, Wout64, bout64,
                                       cbn32, cbn64, scbk64, out, loss_part);
  loss_final<<<1, 256, 0, stream>>>(loss_part, out);
}

// Round 9
// 2892.395 us; speedup vs baseline: 1.1626x; 1.1611x over previous
//
#include <hip/hip_runtime.h>

#define NCB 9
#define KCB 1024
#define CD 8
#define DD 64
#define TT 32768
#define BB 4

#define ZQ_SZ (BB*DD*TT)              // 8388608
#define CODES_OFF ZQ_SZ
#define CODES_SZ (BB*NCB*TT)          // 1179648
#define LAT_OFF (CODES_OFF + CODES_SZ)
#define LAT_SZ (BB*NCB*CD*TT)         // 9437184
#define LOSS_OFF (LAT_OFF + LAT_SZ)   // 19005440

// ---- d_ws byte layout ----
#define OFF_CBN32    0          // 73728 f32  = 294912
#define OFF_CBN64    294912     // 73728 f64  = 589824
#define OFF_SCBK64   884736     // 9216 f64   = 73728
#define OFF_WIN64    958464     // 4608 f64   = 36864
#define OFF_WOUT64   995328     // 4608 f64   = 36864
#define OFF_BIN64    1032192    // 72 f64     = 576
#define OFF_BOUT64   1032768    // 576 f64    = 4608
#define OFF_LOSSPART 1037376    // 1024 f64   = 8192

__global__ void prep_cb(const float* __restrict__ cb,
                        float* __restrict__ cbn32,
                        double* __restrict__ cbn64, double* __restrict__ scbk64) {
  int r = blockIdx.x * blockDim.x + threadIdx.x;
  if (r >= NCB * KCB) return;
  double v[CD], s = 0.0;
#pragma unroll
  for (int c = 0; c < CD; c++) { v[c] = (double)cb[r*CD + c]; s += v[c]*v[c]; }
  double den = fmax(sqrt(s), 1e-12);
  double s2 = 0.0;
#pragma unroll
  for (int c = 0; c < CD; c++) {
    double o = v[c] / den;
    cbn64[r*CD + c] = o;
    cbn32[r*CD + c] = (float)o;
    s2 += o*o;
  }
  scbk64[r] = s2;
}

__global__ void prep_w(const float* __restrict__ W_in, const float* __restrict__ b_in,
                       const float* __restrict__ W_out, const float* __restrict__ b_out,
                       double* __restrict__ Win64, double* __restrict__ bin64,
                       double* __restrict__ Wout64, double* __restrict__ bout64) {
  int i = blockIdx.x * blockDim.x + threadIdx.x;
  if (i < NCB*CD*DD) Win64[i]  = (double)W_in[i];
  if (i < NCB*CD*DD) Wout64[i] = (double)W_out[i];
  if (i < NCB*CD)    bin64[i]  = (double)b_in[i];
  if (i < NCB*DD)    bout64[i] = (double)b_out[i];
}

// Pair-split: lanes l and l+32 co-own position p. Each scans 512 codes and owns
// 32 D-channels; merges are one __shfl_xor(...,32) (f64 add -> bitwise exact).
// __launch_bounds__(256,2): the ONLY empirically-clean allocation config
// (R3/R5: VGPR=128, 0.28 GB). min-waves=4 and waves_per_eu(4,4) both produced
// VGPR=64 + 8.5 GB scratch spill traffic (R4/R6/R7). Do not change this.
// Scan is batch-4: issue 8 independent ds_read_b128 before any dot consumes
// them (R5 measured 210 cyc/k = per-k LDS serialization without this).
__global__ __launch_bounds__(256, 2) void rvq_kernel(
    const float* __restrict__ x,
    const float* __restrict__ cb,
    const double* __restrict__ Win64,
    const double* __restrict__ bin64,
    const double* __restrict__ Wout64,
    const double* __restrict__ bout64,
    const float* __restrict__ cbn32,
    const double* __restrict__ cbn64,
    const double* __restrict__ scbk64,
    float* __restrict__ out,
    double* __restrict__ loss_part) {
  __shared__ __align__(16) float cb_lds[KCB * CD];   // 32 KB
  __shared__ double wsum[4];

  const int lane = threadIdx.x & 63;
  const int wv   = threadIdx.x >> 6;
  const int h    = lane >> 5;                 // half: 0 or 1
  const int p    = blockIdx.x * 128 + wv * 32 + (lane & 31);
  const int b    = p >> 15;                   // TT = 2^15
  const int t    = p & (TT - 1);
  const int dbase = h * 32;

  // my 32 D-channels of the f64 residual chain
  double r[32];
#pragma unroll
  for (int d = 0; d < 32; d++) r[d] = (double)x[(b*DD + dbase + d)*TT + t];

  double lacc = 0.0;

#pragma unroll 1
  for (int i = 0; i < NCB; i++) {
    // ---- stage codebook i into LDS (row-major; scan reads are broadcast)
    __syncthreads();
    {
      const float4* __restrict__ src = (const float4*)(cbn32 + i*KCB*CD);
      float4* __restrict__ dst = (float4*)cb_lds;
#pragma unroll
      for (int c0 = 0; c0 < 8; c0++)
        dst[c0*256 + threadIdx.x] = src[c0*256 + threadIdx.x];
    }
    __syncthreads();

    // ---- in_proj (f64): partial over my 32 d's, one xor-32 merge
    double ze[CD];
    {
      const double* __restrict__ W = Win64 + i*CD*DD + dbase;
#pragma unroll
      for (int c = 0; c < CD; c++) {
        double acc = 0.0;
#pragma unroll
        for (int d = 0; d < 32; d++)
          acc = fma(W[c*DD + d], r[d], acc);
        ze[c] = acc;
      }
#pragma unroll
      for (int c = 0; c < CD; c++) {
        ze[c] += __shfl_xor(ze[c], 32, 64);   // bitwise identical on both lanes
        ze[c] += bin64[i*CD + c];
      }
    }

    // ---- normalize: one f64 division, f32 enc for the scan
    double s0 = 0.0;
#pragma unroll
    for (int c = 0; c < CD; c++) s0 = fma(ze[c], ze[c], s0);
    double inv = 1.0 / fmax(sqrt(s0), 1e-12);
    float encf[CD];
#pragma unroll
    for (int c = 0; c < CD; c++) encf[c] = (float)(ze[c] * inv);

    // ---- f32 max-dot scan, batch-4 rows: load 8 float4 then compute 4 dots
    const float4* __restrict__ lb = (const float4*)(cb_lds + h * (512 * CD));
    float best = -3.402823466e38f, best2 = -3.402823466e38f;
    int bidx = 0;
#pragma unroll 2
    for (int kk = 0; kk < 512; kk += 4) {
      float4 a0 = lb[2*kk + 0], a1 = lb[2*kk + 1];
      float4 b0 = lb[2*kk + 2], b1 = lb[2*kk + 3];
      float4 c0 = lb[2*kk + 4], c1 = lb[2*kk + 5];
      float4 d0 = lb[2*kk + 6], d1 = lb[2*kk + 7];
      float dotA = encf[0]*a0.x; float dotB = encf[0]*b0.x;
      float dotC = encf[0]*c0.x; float dotD = encf[0]*d0.x;
      dotA = fmaf(encf[1], a0.y, dotA); dotB = fmaf(encf[1], b0.y, dotB);
      dotC = fmaf(encf[1], c0.y, dotC); dotD = fmaf(encf[1], d0.y, dotD);
      dotA = fmaf(encf[2], a0.z, dotA); dotB = fmaf(encf[2], b0.z, dotB);
      dotC = fmaf(encf[2], c0.z, dotC); dotD = fmaf(encf[2], d0.z, dotD);
      dotA = fmaf(encf[3], a0.w, dotA); dotB = fmaf(encf[3], b0.w, dotB);
      dotC = fmaf(encf[3], c0.w, dotC); dotD = fmaf(encf[3], d0.w, dotD);
      dotA = fmaf(encf[4], a1.x, dotA); dotB = fmaf(encf[4], b1.x, dotB);
      dotC = fmaf(encf[4], c1.x, dotC); dotD = fmaf(encf[4], d1.x, dotD);
      dotA = fmaf(encf[5], a1.y, dotA); dotB = fmaf(encf[5], b1.y, dotB);
      dotC = fmaf(encf[5], c1.y, dotC); dotD = fmaf(encf[5], d1.y, dotD);
      dotA = fmaf(encf[6], a1.z, dotA); dotB = fmaf(encf[6], b1.z, dotB);
      dotC = fmaf(encf[6], c1.z, dotC); dotD = fmaf(encf[6], d1.z, dotD);
      dotA = fmaf(encf[7], a1.w, dotA); dotB = fmaf(encf[7], b1.w, dotB);
      dotC = fmaf(encf[7], c1.w, dotC); dotD = fmaf(encf[7], d1.w, dotD);
      float ob;
      ob = best; best2 = __builtin_amdgcn_fmed3f(ob, best2, dotA);
      best = fmaxf(ob, dotA); bidx = (dotA > ob) ? (h*512 + kk + 0) : bidx;
      ob = best; best2 = __builtin_amdgcn_fmed3f(ob, best2, dotB);
      best = fmaxf(ob, dotB); bidx = (dotB > ob) ? (h*512 + kk + 1) : bidx;
      ob = best; best2 = __builtin_amdgcn_fmed3f(ob, best2, dotC);
      best = fmaxf(ob, dotC); bidx = (dotC > ob) ? (h*512 + kk + 2) : bidx;
      ob = best; best2 = __builtin_amdgcn_fmed3f(ob, best2, dotD);
      best = fmaxf(ob, dotD); bidx = (dotD > ob) ? (h*512 + kk + 3) : bidx;
    }

    // ---- merge top-2 + argmax across the pair (xor 32)
    {
      float obest  = __shfl_xor(best, 32, 64);
      float obest2 = __shfl_xor(best2, 32, 64);
      int   okidx  = __shfl_xor(bidx, 32, 64);
      best2 = fmaxf(fminf(best, obest), fmaxf(best2, obest2));
      bool take = (obest > best) || (obest == best && okidx < bidx);
      best = fmaxf(best, obest);
      bidx = take ? okidx : bidx;
    }

    // ---- near-tie: authoritative f64 rescan (pair-uniform trigger, rare)
    if (best - best2 < 1.2e-5f) {
      const double* __restrict__ cb64 = cbn64 + (i*KCB + h*512)*CD;
      const double* __restrict__ s64  = scbk64 + i*KCB + h*512;
      double enc64[CD], s_enc = 0.0;
#pragma unroll
      for (int c = 0; c < CD; c++) {
        enc64[c] = ze[c] * inv;
        s_enc = fma(enc64[c], enc64[c], s_enc);
      }
      double bd = 1e300;
      int bk = h*512;
#pragma unroll 2
      for (int kk = 0; kk < 512; kk++) {
        double dot = 0.0;
#pragma unroll
        for (int c = 0; c < CD; c++)
          dot = fma(enc64[c], cb64[kk*CD + c], dot);
        double dist = fma(-2.0, dot, s_enc) + s64[kk];
        if (dist < bd) { bd = dist; bk = h*512 + kk; }   // first index on ties
      }
      {
        double od = __shfl_xor(bd, 32, 64);
        int    ok = __shfl_xor(bk, 32, 64);
        bool take = (od < bd) || (od == bd && ok < bk);
        bd = take ? od : bd;
        bk = take ? ok : bk;
      }
      bidx = bk;
    }

    // ---- gather raw codebook row (pair-uniform address)
    const float4* __restrict__ qrow = (const float4*)(cb + (i*KCB + bidx)*CD);
    float4 q0 = qrow[0], q1 = qrow[1];
    double zq[CD] = {(double)q0.x, (double)q0.y, (double)q0.z, (double)q0.w,
                     (double)q1.x, (double)q1.y, (double)q1.z, (double)q1.w};

    // ---- loss once per position (h==0 half only)
    if (h == 0) {
#pragma unroll
      for (int c = 0; c < CD; c++) {
        double dlt = ze[c] - zq[c];
        lacc = fma(dlt, dlt, lacc);
      }
    }

    // ---- out_proj (f64) on my 32 d's + residual update
    {
      const double* __restrict__ Wo = Wout64 + (i*DD + dbase)*CD;
#pragma unroll
      for (int d = 0; d < 32; d++) {
        double acc = bout64[i*DD + dbase + d];
#pragma unroll
        for (int c = 0; c < CD; c++)
          acc = fma(Wo[d*CD + c], zq[c], acc);
        r[d] -= acc;
      }
    }

    // ---- codes (h==0) + latents (each half writes 4 channels)
    if (h == 0) out[CODES_OFF + (b*NCB + i)*TT + t] = (float)bidx;
#pragma unroll
    for (int cc = 0; cc < 4; cc++)
      out[LAT_OFF + (b*NCB*CD + i*CD + 4*h + cc)*TT + t] = (float)ze[4*h + cc];
  }

  // ---- z_q = x - residual_final (my 32 d's)
#pragma unroll
  for (int d = 0; d < 32; d++)
    out[(b*DD + dbase + d)*TT + t] =
        (float)((double)x[(b*DD + dbase + d)*TT + t] - r[d]);

  // ---- deterministic loss reduction (h==1 lanes hold 0)
#pragma unroll
  for (int off = 32; off > 0; off >>= 1)
    lacc += __shfl_down(lacc, off, 64);
  if ((threadIdx.x & 63) == 0) wsum[wv] = lacc;
  __syncthreads();
  if (threadIdx.x == 0)
    loss_part[blockIdx.x] = wsum[0] + wsum[1] + wsum[2] + wsum[3];
}

__global__ void loss_final(const double* __restrict__ loss_part,
                           float* __restrict__ out) {
  __shared__ double sh[256];
  double s = 0.0;
#pragma unroll
  for (int i = 0; i < 4; i++) s += loss_part[threadIdx.x + i*256];
  sh[threadIdx.x] = s;
  __syncthreads();
  for (int off = 128; off > 0; off >>= 1) {
    if (threadIdx.x < off) sh[threadIdx.x] += sh[threadIdx.x + off];
    __syncthreads();
  }
  if (threadIdx.x == 0) {
    double v = sh[0] / ((double)NCB * (double)BB * (double)CD * (double)TT);
    out[LOSS_OFF]     = (float)v;   // commit
    out[LOSS_OFF + 1] = (float)v;   // cb_loss (equal in forward value)
  }
}

extern "C" void kernel_launch(void* const* d_in, const int* in_sizes, int n_in,
                              void* d_out, int out_size, void* d_ws, size_t ws_size,
                              hipStream_t stream) {
  const float* x     = (const float*)d_in[0];
  const float* W_in  = (const float*)d_in[1];
  const float* b_in  = (const float*)d_in[2];
  const float* cb    = (const float*)d_in[3];
  const float* W_out = (const float*)d_in[4];
  const float* b_out = (const float*)d_in[5];
  float* out = (float*)d_out;

  char* ws = (char*)d_ws;
  float*  cbn32  = (float*)(ws + OFF_CBN32);
  double* cbn64  = (double*)(ws + OFF_CBN64);
  double* scbk64 = (double*)(ws + OFF_SCBK64);
  double* Win64  = (double*)(ws + OFF_WIN64);
  double* Wout64 = (double*)(ws + OFF_WOUT64);
  double* bin64  = (double*)(ws + OFF_BIN64);
  double* bout64 = (double*)(ws + OFF_BOUT64);
  double* loss_part = (double*)(ws + OFF_LOSSPART);

  prep_cb<<<(NCB*KCB + 255)/256, 256, 0, stream>>>(cb, cbn32, cbn64, scbk64);
  prep_w<<<(NCB*CD*DD + 255)/256, 256, 0, stream>>>(W_in, b_in, W_out, b_out,
                                                    Win64, bin64, Wout64, bout64);
  rvq_kernel<<<1024, 256, 0, stream>>>(x, cb, Win64, bin64, Wout64, bout64,
                                       cbn32, cbn64, scbk64, out, loss_part);
  loss_final<<<1, 256, 0, stream>>>(loss_part, out);
}

// Round 10
// 1533.782 us; speedup vs baseline: 2.1925x; 1.8858x over previous
//
#include <hip/hip_runtime.h>

#define NCB 9
#define KCB 1024
#define CD 8
#define DD 64
#define TT 32768
#define BB 4

#define ZQ_SZ (BB*DD*TT)              // 8388608
#define CODES_OFF ZQ_SZ
#define CODES_SZ (BB*NCB*TT)          // 1179648
#define LAT_OFF (CODES_OFF + CODES_SZ)
#define LAT_SZ (BB*NCB*CD*TT)         // 9437184
#define LOSS_OFF (LAT_OFF + LAT_SZ)   // 19005440

// ---- d_ws byte layout ----
#define OFF_CBN32    0          // 73728 f32  = 294912
#define OFF_CBN64    294912     // 73728 f64  = 589824
#define OFF_SCBK64   884736     // 9216 f64   = 73728
#define OFF_WIN64    958464     // 4608 f64   = 36864
#define OFF_WOUT64   995328     // 4608 f64   = 36864
#define OFF_BIN64    1032192    // 72 f64     = 576
#define OFF_BOUT64   1032768    // 576 f64    = 4608
#define OFF_LOSSPART 1037376    // 512 f64    = 4096

__global__ void prep_cb(const float* __restrict__ cb,
                        float* __restrict__ cbn32,
                        double* __restrict__ cbn64, double* __restrict__ scbk64) {
  int r = blockIdx.x * blockDim.x + threadIdx.x;
  if (r >= NCB * KCB) return;
  double v[CD], s = 0.0;
#pragma unroll
  for (int c = 0; c < CD; c++) { v[c] = (double)cb[r*CD + c]; s += v[c]*v[c]; }
  double den = fmax(sqrt(s), 1e-12);
  double s2 = 0.0;
#pragma unroll
  for (int c = 0; c < CD; c++) {
    double o = v[c] / den;
    cbn64[r*CD + c] = o;
    cbn32[r*CD + c] = (float)o;
    s2 += o*o;
  }
  scbk64[r] = s2;
}

__global__ void prep_w(const float* __restrict__ W_in, const float* __restrict__ b_in,
                       const float* __restrict__ W_out, const float* __restrict__ b_out,
                       double* __restrict__ Win64, double* __restrict__ bin64,
                       double* __restrict__ Wout64, double* __restrict__ bout64) {
  int i = blockIdx.x * blockDim.x + threadIdx.x;
  if (i < NCB*CD*DD) Win64[i]  = (double)W_in[i];
  if (i < NCB*CD*DD) Wout64[i] = (double)W_out[i];
  if (i < NCB*CD)    bin64[i]  = (double)b_in[i];
  if (i < NCB*DD)    bout64[i] = (double)b_out[i];
}

// Thread-per-position (R5 clean structure: VGPR=128, 0.285 GB traffic) with the
// scan rewritten batch-4: 8 independent ds_read_b128 issue before any dot
// consumes them (R5 measured 210 cyc/k = per-k LDS serialization without it).
// __launch_bounds__(256,2) is the only empirically-clean allocation config;
// all pair-split variants spilled (R4/R6/R7/R9: 6.8-8.6 GB scratch traffic).
__global__ __launch_bounds__(256, 2) void rvq_kernel(
    const float* __restrict__ x,
    const float* __restrict__ cb,
    const double* __restrict__ Win64,
    const double* __restrict__ bin64,
    const double* __restrict__ Wout64,
    const double* __restrict__ bout64,
    const float* __restrict__ cbn32,
    const double* __restrict__ cbn64,
    const double* __restrict__ scbk64,
    float* __restrict__ out,
    double* __restrict__ loss_part) {
  __shared__ __align__(16) float cb_lds[KCB * CD];   // 32 KB
  __shared__ double wsum[4];

  const int tid = blockIdx.x * 256 + threadIdx.x;
  const int b = tid >> 15;            // TT = 2^15
  const int t = tid & (TT - 1);

  // residual chain in f64 — tracks the f64 golden reference end-to-end
  double r[DD];
#pragma unroll
  for (int d = 0; d < DD; d++) r[d] = (double)x[(b*DD + d)*TT + t];

  double lacc = 0.0;

#pragma unroll 1
  for (int i = 0; i < NCB; i++) {
    // ---- stage codebook i into LDS (row-major; scan reads are broadcast)
    __syncthreads();
    {
      const float4* __restrict__ src = (const float4*)(cbn32 + i*KCB*CD);
      float4* __restrict__ dst = (float4*)cb_lds;
#pragma unroll
      for (int c0 = 0; c0 < 8; c0++)
        dst[c0*256 + threadIdx.x] = src[c0*256 + threadIdx.x];
    }
    __syncthreads();

    // ---- in_proj (f64): z_e = W_in[i] @ r + b_in[i]  (W uniform -> scalar loads)
    double ze[CD];
#pragma unroll
    for (int c = 0; c < CD; c++) ze[c] = bin64[i*CD + c];
#pragma unroll
    for (int c = 0; c < CD; c++) {
#pragma unroll
      for (int d = 0; d < DD; d++)
        ze[c] = fma(Win64[(i*CD + c)*DD + d], r[d], ze[c]);
    }

    // ---- normalize: one f64 division, f32 enc for the scan
    double s0 = 0.0;
#pragma unroll
    for (int c = 0; c < CD; c++) s0 = fma(ze[c], ze[c], s0);
    double inv = 1.0 / fmax(sqrt(s0), 1e-12);
    float encf[CD];
#pragma unroll
    for (int c = 0; c < CD; c++) encf[c] = (float)(ze[c] * inv);

    // ---- f32 max-dot scan, batch-4 rows: load 8 float4 then compute 4 dots
    const float4* __restrict__ lb = (const float4*)cb_lds;
    float best = -3.402823466e38f, best2 = -3.402823466e38f;
    int bidx = 0;
#pragma unroll 2
    for (int kk = 0; kk < KCB; kk += 4) {
      float4 a0 = lb[2*kk + 0], a1 = lb[2*kk + 1];
      float4 b0 = lb[2*kk + 2], b1 = lb[2*kk + 3];
      float4 c0 = lb[2*kk + 4], c1 = lb[2*kk + 5];
      float4 d0 = lb[2*kk + 6], d1 = lb[2*kk + 7];
      float dotA = encf[0]*a0.x; float dotB = encf[0]*b0.x;
      float dotC = encf[0]*c0.x; float dotD = encf[0]*d0.x;
      dotA = fmaf(encf[1], a0.y, dotA); dotB = fmaf(encf[1], b0.y, dotB);
      dotC = fmaf(encf[1], c0.y, dotC); dotD = fmaf(encf[1], d0.y, dotD);
      dotA = fmaf(encf[2], a0.z, dotA); dotB = fmaf(encf[2], b0.z, dotB);
      dotC = fmaf(encf[2], c0.z, dotC); dotD = fmaf(encf[2], d0.z, dotD);
      dotA = fmaf(encf[3], a0.w, dotA); dotB = fmaf(encf[3], b0.w, dotB);
      dotC = fmaf(encf[3], c0.w, dotC); dotD = fmaf(encf[3], d0.w, dotD);
      dotA = fmaf(encf[4], a1.x, dotA); dotB = fmaf(encf[4], b1.x, dotB);
      dotC = fmaf(encf[4], c1.x, dotC); dotD = fmaf(encf[4], d1.x, dotD);
      dotA = fmaf(encf[5], a1.y, dotA); dotB = fmaf(encf[5], b1.y, dotB);
      dotC = fmaf(encf[5], c1.y, dotC); dotD = fmaf(encf[5], d1.y, dotD);
      dotA = fmaf(encf[6], a1.z, dotA); dotB = fmaf(encf[6], b1.z, dotB);
      dotC = fmaf(encf[6], c1.z, dotC); dotD = fmaf(encf[6], d1.z, dotD);
      dotA = fmaf(encf[7], a1.w, dotA); dotB = fmaf(encf[7], b1.w, dotB);
      dotC = fmaf(encf[7], c1.w, dotC); dotD = fmaf(encf[7], d1.w, dotD);
      float ob;
      ob = best; best2 = __builtin_amdgcn_fmed3f(ob, best2, dotA);
      best = fmaxf(ob, dotA); bidx = (dotA > ob) ? (kk + 0) : bidx;
      ob = best; best2 = __builtin_amdgcn_fmed3f(ob, best2, dotB);
      best = fmaxf(ob, dotB); bidx = (dotB > ob) ? (kk + 1) : bidx;
      ob = best; best2 = __builtin_amdgcn_fmed3f(ob, best2, dotC);
      best = fmaxf(ob, dotC); bidx = (dotC > ob) ? (kk + 2) : bidx;
      ob = best; best2 = __builtin_amdgcn_fmed3f(ob, best2, dotD);
      best = fmaxf(ob, dotD); bidx = (dotD > ob) ? (kk + 3) : bidx;
    }

    // ---- near-tie: authoritative f64 rescan (rare, exec-masked)
    if (best - best2 < 1.2e-5f) {
      const double* __restrict__ cb64 = cbn64 + i*KCB*CD;
      const double* __restrict__ s64  = scbk64 + i*KCB;
      double enc64[CD], s_enc = 0.0;
#pragma unroll
      for (int c = 0; c < CD; c++) {
        enc64[c] = ze[c] * inv;
        s_enc = fma(enc64[c], enc64[c], s_enc);
      }
      double bd = 1e300;
      int bk = 0;
#pragma unroll 4
      for (int k = 0; k < KCB; k++) {
        double dot = 0.0;
#pragma unroll
        for (int c = 0; c < CD; c++)
          dot = fma(enc64[c], cb64[k*CD + c], dot);
        double dist = fma(-2.0, dot, s_enc) + s64[k];
        if (dist < bd) { bd = dist; bk = k; }    // first-index tie-break
      }
      bidx = bk;
    }

    // ---- gather raw codebook row (f32 values, exact in f64)
    const float4* __restrict__ qrow = (const float4*)(cb + (i*KCB + bidx)*CD);
    float4 q0 = qrow[0], q1 = qrow[1];
    double zq[CD] = {(double)q0.x, (double)q0.y, (double)q0.z, (double)q0.w,
                     (double)q1.x, (double)q1.y, (double)q1.z, (double)q1.w};

    // ---- losses (commit == cb_loss in forward value)
#pragma unroll
    for (int c = 0; c < CD; c++) {
      double dlt = ze[c] - zq[c];
      lacc = fma(dlt, dlt, lacc);
    }

    // ---- out_proj (f64) + residual update
#pragma unroll
    for (int d = 0; d < DD; d++) {
      double acc = bout64[i*DD + d];
#pragma unroll
      for (int c = 0; c < CD; c++)
        acc = fma(Wout64[(i*DD + d)*CD + c], zq[c], acc);
      r[d] -= acc;
    }

    // ---- codes (as float) and latents (= z_e) — contiguous wave stores
    out[CODES_OFF + (b*NCB + i)*TT + t] = (float)bidx;
#pragma unroll
    for (int c = 0; c < CD; c++)
      out[LAT_OFF + (b*NCB*CD + i*CD + c)*TT + t] = (float)ze[c];
  }

  // ---- z_q = x - residual_final
#pragma unroll
  for (int d = 0; d < DD; d++)
    out[(b*DD + d)*TT + t] = (float)((double)x[(b*DD + d)*TT + t] - r[d]);

  // ---- deterministic loss reduction
#pragma unroll
  for (int off = 32; off > 0; off >>= 1)
    lacc += __shfl_down(lacc, off, 64);
  int wv = threadIdx.x >> 6;
  if ((threadIdx.x & 63) == 0) wsum[wv] = lacc;
  __syncthreads();
  if (threadIdx.x == 0)
    loss_part[blockIdx.x] = wsum[0] + wsum[1] + wsum[2] + wsum[3];
}

__global__ void loss_final(const double* __restrict__ loss_part,
                           float* __restrict__ out) {
  __shared__ double sh[256];
  double s = loss_part[threadIdx.x] + loss_part[threadIdx.x + 256];
  sh[threadIdx.x] = s;
  __syncthreads();
  for (int off = 128; off > 0; off >>= 1) {
    if (threadIdx.x < off) sh[threadIdx.x] += sh[threadIdx.x + off];
    __syncthreads();
  }
  if (threadIdx.x == 0) {
    double v = sh[0] / ((double)NCB * (double)BB * (double)CD * (double)TT);
    out[LOSS_OFF]     = (float)v;   // commit
    out[LOSS_OFF + 1] = (float)v;   // cb_loss (equal in forward value)
  }
}

extern "C" void kernel_launch(void* const* d_in, const int* in_sizes, int n_in,
                              void* d_out, int out_size, void* d_ws, size_t ws_size,
                              hipStream_t stream) {
  const float* x     = (const float*)d_in[0];
  const float* W_in  = (const float*)d_in[1];
  const float* b_in  = (const float*)d_in[2];
  const float* cb    = (const float*)d_in[3];
  const float* W_out = (const float*)d_in[4];
  const float* b_out = (const float*)d_in[5];
  float* out = (float*)d_out;

  char* ws = (char*)d_ws;
  float*  cbn32  = (float*)(ws + OFF_CBN32);
  double* cbn64  = (double*)(ws + OFF_CBN64);
  double* scbk64 = (double*)(ws + OFF_SCBK64);
  double* Win64  = (double*)(ws + OFF_WIN64);
  double* Wout64 = (double*)(ws + OFF_WOUT64);
  double* bin64  = (double*)(ws + OFF_BIN64);
  double* bout64 = (double*)(ws + OFF_BOUT64);
  double* loss_part = (double*)(ws + OFF_LOSSPART);

  prep_cb<<<(NCB*KCB + 255)/256, 256, 0, stream>>>(cb, cbn32, cbn64, scbk64);
  prep_w<<<(NCB*CD*DD + 255)/256, 256, 0, stream>>>(W_in, b_in, W_out, b_out,
                                                    Win64, bin64, Wout64, bout64);
  rvq_kernel<<<(BB*TT)/256, 256, 0, stream>>>(x, cb, Win64, bin64, Wout64, bout64,
                                              cbn32, cbn64, scbk64, out, loss_part);
  loss_final<<<1, 256, 0, stream>>>(loss_part, out);
}